// Round 6
// baseline (761.186 us; speedup 1.0000x reference)
//
#include <hip/hip_runtime.h>

#define NN 50000
#define NE 800000

// ws element offsets (4-byte units), 64-aligned; O_EINFO 8B-aligned
#define O_DEGIN   0
#define O_DEGOUT  50048
#define O_ROWPTR  100096
#define O_CURSOR  150208
#define O_EINFO   200256
#define O_FEATN   1800256
#define O_ZF      3400256
#define O_ZNRD    3600320
#define O_VV      3800384
#define O_EZ      3800832
#define O_NFT     4600832
#define O_WDENT   6200832
#define O_YACCT   6450880
#define O_H1      19250880
// end 20850880 elems = ~83.4 MB

// ---------------- setup kernels ----------------

__global__ __launch_bounds__(256) void k_deg(const int* __restrict__ src,
                                             const int* __restrict__ dst,
                                             int* degin, int* degout) {
    int e = blockIdx.x * 256 + threadIdx.x;
    if (e < NE) {
        atomicAdd(&degin[dst[e]], 1);
        atomicAdd(&degout[src[e]], 1);
    }
}

// single block, shuffle-based scan: 3 barriers per 16384-chunk
__global__ __launch_bounds__(1024) void k_scan(const int* __restrict__ degin,
                                               int* rowptr, int* cursor) {
    __shared__ int swsum[16];
    __shared__ int stot;
    int t = threadIdx.x;
    int lane = t & 63, w = t >> 6;
    int carry = 0;
    for (int ch = 0; ch < 4; ch++) {
        int base = ch * 16384 + t * 16;
        int v[16];
        int s = 0;
#pragma unroll
        for (int j = 0; j < 16; j++) {
            v[j] = (base + j < NN) ? degin[base + j] : 0;
            s += v[j];
        }
        // wave-inclusive scan of s
        int incl = s;
#pragma unroll
        for (int off = 1; off < 64; off <<= 1) {
            int x = __shfl_up(incl, off, 64);
            if (lane >= off) incl += x;
        }
        if (lane == 63) swsum[w] = incl;
        __syncthreads();
        if (w == 0) {
            int y = (lane < 16) ? swsum[lane] : 0;
            int yi = y;
#pragma unroll
            for (int off = 1; off < 16; off <<= 1) {
                int x = __shfl_up(yi, off, 64);
                if (lane >= off) yi += x;
            }
            if (lane < 16) swsum[lane] = yi - y;   // exclusive wave offsets
            if (lane == 15) stot = yi;             // chunk total
        }
        __syncthreads();
        int excl = carry + swsum[w] + (incl - s);
#pragma unroll
        for (int j = 0; j < 16; j++) {
            if (base + j < NN) { rowptr[base + j] = excl; cursor[base + j] = excl; }
            excl += v[j];
        }
        carry += stot;
        __syncthreads();   // protect swsum/stot before next chunk overwrites
    }
    if (t == 0) rowptr[NN] = carry;
}

__global__ __launch_bounds__(256) void k_scatter(const int* __restrict__ src,
                                                 const int* __restrict__ dst,
                                                 const int* __restrict__ eid,
                                                 int* cursor, int2* einfo) {
    int e = blockIdx.x * 256 + threadIdx.x;
    if (e >= NE) return;
    int slot = atomicAdd(&cursor[dst[e]], 1);
    einfo[slot] = make_int2(src[e] | (eid[e] << 20), e);
}

// ---------------- per-layer kernels ----------------

// vvec[0:128]=ve[r][k] (We_r@aw2), [128:256]=vf[r][k] (Wf_r@aw2),
// [256:384]=vd[r][k] (Wd_r@aw2)
__global__ __launch_bounds__(384) void k_prevec(const float* __restrict__ Wr,
                                                const float* __restrict__ attw,
                                                float* __restrict__ vvec) {
    int t = threadIdx.x;
    int r = (t >> 5) & 3, k = t & 31, part = t >> 7;
    int row = (part == 0) ? (32 + k) : (part == 1) ? k : (64 + k);
    const float* wrow = Wr + (size_t)r * 3072 + row * 32;
    float s = 0.f;
#pragma unroll
    for (int c = 0; c < 32; c++) s += wrow[c] * attw[32 + c];
    vvec[t] = s;
}

// Thread per node: featn row (for k_agg gathers), nfT column (for k_post),
// zF[r][n], znrd[r][n]
__global__ __launch_bounds__(128) void k_nodeproj(const float* __restrict__ feat,
                                                  const float* __restrict__ nfeat,
                                                  const float* __restrict__ attw,
                                                  const float* __restrict__ vvec,
                                                  const int* __restrict__ degout,
                                                  float* __restrict__ featn,
                                                  float* __restrict__ nfT,
                                                  float* __restrict__ zF,
                                                  float* __restrict__ znrd) {
    int n = blockIdx.x * 128 + threadIdx.x;
    if (n >= NN) return;
    int dg = degout[n];
    float sc0 = rsqrtf((float)(dg > 1 ? dg : 1));
    const float* fin = feat + (size_t)n * 32;
    const float* nin = nfeat + (size_t)n * 32;
    float fv[32], nv[32];
#pragma unroll
    for (int k = 0; k < 32; k += 4) {
        float4 f4 = *(const float4*)&fin[k];
        fv[k] = f4.x * sc0; fv[k + 1] = f4.y * sc0;
        fv[k + 2] = f4.z * sc0; fv[k + 3] = f4.w * sc0;
        float4 n4 = *(const float4*)&nin[k];
        nv[k] = n4.x; nv[k + 1] = n4.y; nv[k + 2] = n4.z; nv[k + 3] = n4.w;
    }
    float* fo = featn + (size_t)n * 32;
#pragma unroll
    for (int k = 0; k < 32; k += 4)
        *(float4*)&fo[k] = make_float4(fv[k], fv[k + 1], fv[k + 2], fv[k + 3]);
#pragma unroll
    for (int k = 0; k < 32; k++) nfT[(size_t)k * NN + n] = nv[k];  // coalesced/k
    float zn = 0.f;
#pragma unroll
    for (int k = 0; k < 32; k++) zn += nv[k] * attw[k];
#pragma unroll
    for (int r = 0; r < 4; r++) {
        float zf = 0.f, zd = 0.f;
        const float* vf = vvec + 128 + r * 32;
        const float* vd = vvec + 256 + r * 32;
#pragma unroll
        for (int k = 0; k < 32; k++) { zf += fv[k] * vf[k]; zd += nv[k] * vd[k]; }
        zF[r * NN + n] = zf;
        znrd[r * NN + n] = zn + zd;
    }
}

// Flat edge-parallel: ez[e] = exp(leaky(znrd[r][d] + zF[r][s] + efeat[e].ve_r))
__global__ __launch_bounds__(256) void k_ez(const int* __restrict__ src,
                                            const int* __restrict__ dst,
                                            const int* __restrict__ eid,
                                            const float* __restrict__ efeat,
                                            const float* __restrict__ zF,
                                            const float* __restrict__ znrd,
                                            const float* __restrict__ vvec,
                                            float* __restrict__ ez) {
    int e = blockIdx.x * 256 + threadIdx.x;   // 3125*256 = NE exact
    int s = src[e], d = dst[e], r = eid[e];
    const float* er = efeat + (size_t)e * 32;
    float d0 = 0.f, d1 = 0.f, d2 = 0.f, d3 = 0.f;
#pragma unroll
    for (int k = 0; k < 32; k += 4) {
        float4 f = *(const float4*)&er[k];
        d0 += f.x * vvec[k]       + f.y * vvec[k + 1]
            + f.z * vvec[k + 2]   + f.w * vvec[k + 3];
        d1 += f.x * vvec[32 + k]  + f.y * vvec[33 + k]
            + f.z * vvec[34 + k]  + f.w * vvec[35 + k];
        d2 += f.x * vvec[64 + k]  + f.y * vvec[65 + k]
            + f.z * vvec[66 + k]  + f.w * vvec[67 + k];
        d3 += f.x * vvec[96 + k]  + f.y * vvec[97 + k]
            + f.z * vvec[98 + k]  + f.w * vvec[99 + k];
    }
    float dot = (r == 0) ? d0 : (r == 1) ? d1 : (r == 2) ? d2 : d3;
    float z = znrd[r * NN + d] + zF[r * NN + s] + dot;
    z = z > 0.f ? z : 0.01f * z;      // leaky_relu
    ez[e] = __expf(z);                // softmax max-shift cancels
}

// Wave per node, lane=(p,c): ez-weighted raw-row accumulation, software-
// pipelined gathers. Output transposed via LDS -> yaccT[k][n] (SoA for k_post).
__global__ __launch_bounds__(512) void k_agg(const int* __restrict__ rowptr,
                                             const int2* __restrict__ einfo,
                                             const float* __restrict__ ez,
                                             const float* __restrict__ efeat,
                                             const float* __restrict__ featn,
                                             float* __restrict__ yaccT,
                                             float* __restrict__ wdenT) {
    __shared__ float sT[256 * 9];   // [k][wid] padded (+1 col) vs bank aliasing
    int tid = threadIdx.x;
    int lane = tid & 63;
    int wid = tid >> 6;
    int n0 = blockIdx.x * 8;
    int n = n0 + wid;               // 6250*8 = 50000 exact
    int c = lane & 31;
    int p = lane >> 5;

    int rp0 = rowptr[n];
    int deg = rowptr[n + 1] - rp0;

    float yf0 = 0.f, yf1 = 0.f, yf2 = 0.f, yf3 = 0.f;
    float ye0 = 0.f, ye1 = 0.f, ye2 = 0.f, ye3 = 0.f;
    float w0 = 0.f, w1 = 0.f, w2 = 0.f, w3 = 0.f, den = 0.f;

    // pipeline: einfo 2-ahead, gathers 1-ahead
    int2 meA = make_int2(0, 0), meB = make_int2(0, 0);
    float ezA = 0.f, efA = 0.f, fnA = 0.f;
    if (p < deg) {
        meA = einfo[rp0 + p];
        ezA = ez[meA.y];
        efA = efeat[(size_t)meA.y * 32 + c];
        fnA = featn[(size_t)(meA.x & 0xFFFFF) * 32 + c];
    }
    if (p + 2 < deg) meB = einfo[rp0 + p + 2];

    for (int t = p; t < deg; t += 2) {
        float ezB = 0.f, efB = 0.f, fnB = 0.f;
        int2 meC = make_int2(0, 0);
        if (t + 2 < deg) {
            ezB = ez[meB.y];
            efB = efeat[(size_t)meB.y * 32 + c];
            fnB = featn[(size_t)(meB.x & 0xFFFFF) * 32 + c];
        }
        if (t + 4 < deg) meC = einfo[rp0 + t + 4];
        int rb = meA.x >> 20;
        float e0 = (rb == 0) ? ezA : 0.f;
        float e1 = (rb == 1) ? ezA : 0.f;
        float e2 = (rb == 2) ? ezA : 0.f;
        float e3 = (rb == 3) ? ezA : 0.f;
        yf0 += e0 * fnA; yf1 += e1 * fnA; yf2 += e2 * fnA; yf3 += e3 * fnA;
        ye0 += e0 * efA; ye1 += e1 * efA; ye2 += e2 * efA; ye3 += e3 * efA;
        w0 += e0; w1 += e1; w2 += e2; w3 += e3;
        den += ezA;
        meA = meB; ezA = ezB; efA = efB; fnA = fnB; meB = meC;
    }

    // fold halves
    yf0 += __shfl_xor(yf0, 32); yf1 += __shfl_xor(yf1, 32);
    yf2 += __shfl_xor(yf2, 32); yf3 += __shfl_xor(yf3, 32);
    ye0 += __shfl_xor(ye0, 32); ye1 += __shfl_xor(ye1, 32);
    ye2 += __shfl_xor(ye2, 32); ye3 += __shfl_xor(ye3, 32);
    w0 += __shfl_xor(w0, 32); w1 += __shfl_xor(w1, 32);
    w2 += __shfl_xor(w2, 32); w3 += __shfl_xor(w3, 32);
    den += __shfl_xor(den, 32);

    if (lane < 5) {
        float wv = (lane == 0) ? w0 : (lane == 1) ? w1 : (lane == 2) ? w2
                 : (lane == 3) ? w3 : den;
        wdenT[lane * NN + n] = wv;
    }

    // LDS transpose: lane (p,c) holds rows k=(4p+jj)*32+c for this node (col wid)
    {
        int kb = 128 * p + c;
        sT[(kb +  0) * 9 + wid] = p ? ye0 : yf0;
        sT[(kb + 32) * 9 + wid] = p ? ye1 : yf1;
        sT[(kb + 64) * 9 + wid] = p ? ye2 : yf2;
        sT[(kb + 96) * 9 + wid] = p ? ye3 : yf3;
    }
    __syncthreads();
    // coalesced-ish write: thread -> (row k = tid>>1, 4 nodes)
    int k = tid >> 1, hf = tid & 1;
    float4 v = make_float4(sT[k * 9 + hf * 4 + 0], sT[k * 9 + hf * 4 + 1],
                           sT[k * 9 + hf * 4 + 2], sT[k * 9 + hf * 4 + 3]);
    *(float4*)&yaccT[(size_t)k * NN + n0 + hf * 4] = v;
}

// Thread per node, all loads SoA-coalesced, all weights wave-uniform (SGPR):
// num GEMV (K=416) + loop_w + normalize + fused AMRM + relu.
__global__ __launch_bounds__(256) void k_post(const int* __restrict__ rowptr,
                                              const float* __restrict__ yaccT,
                                              const float* __restrict__ wdenT,
                                              const float* __restrict__ nfT,
                                              const float* __restrict__ Wr,
                                              const float* __restrict__ lw,
                                              const float* __restrict__ hbias,
                                              const float* __restrict__ aW,
                                              const float* __restrict__ ab,
                                              const float* __restrict__ aa,
                                              float* __restrict__ out) {
    int n = blockIdx.x * 256 + threadIdx.x;
    if (n >= NN) return;
    int deg = rowptr[n + 1] - rowptr[n];
    float den = wdenT[4 * NN + n];
    float invden = (deg > 0) ? 1.f / den : 0.f;

    float nv[32];
#pragma unroll
    for (int k = 0; k < 32; k++) nv[k] = nfT[(size_t)k * NN + n];   // coalesced

    float acc[32];
#pragma unroll
    for (int i = 0; i < 32; i++) acc[i] = 0.f;
#pragma unroll
    for (int r = 0; r < 4; r++) {
        const float* W = Wr + (size_t)r * 3072;
        float wr = wdenT[r * NN + n];
        const float* ufc = yaccT + (size_t)(r * 32) * NN + n;
        const float* uec = yaccT + (size_t)(128 + r * 32) * NN + n;
        for (int k4 = 0; k4 < 32; k4 += 4) {
            float a0 = ufc[(size_t)(k4 + 0) * NN], a1 = ufc[(size_t)(k4 + 1) * NN];
            float a2 = ufc[(size_t)(k4 + 2) * NN], a3 = ufc[(size_t)(k4 + 3) * NN];
            float b0 = uec[(size_t)(k4 + 0) * NN], b1 = uec[(size_t)(k4 + 1) * NN];
            float b2 = uec[(size_t)(k4 + 2) * NN], b3 = uec[(size_t)(k4 + 3) * NN];
            float g0 = wr * nv[k4],     g1 = wr * nv[k4 + 1];
            float g2 = wr * nv[k4 + 2], g3 = wr * nv[k4 + 3];
            const float* Wk = W + k4 * 32;
#pragma unroll
            for (int i = 0; i < 32; i++)
                acc[i] += a0 * Wk[i]        + a1 * Wk[32 + i]
                        + a2 * Wk[64 + i]   + a3 * Wk[96 + i]
                        + b0 * Wk[1024 + i] + b1 * Wk[1056 + i]
                        + b2 * Wk[1088 + i] + b3 * Wk[1120 + i]
                        + g0 * Wk[2048 + i] + g1 * Wk[2080 + i]
                        + g2 * Wk[2112 + i] + g3 * Wk[2144 + i];
        }
    }

    float hsc = rsqrtf((float)(deg > 1 ? deg : 1));
    float h[32];
#pragma unroll
    for (int i = 0; i < 32; i++) h[i] = acc[i] * invden;
    for (int k4 = 0; k4 < 32; k4 += 4) {
        const float* Lk = lw + k4 * 32;
#pragma unroll
        for (int i = 0; i < 32; i++)
            h[i] += nv[k4] * Lk[i] + nv[k4 + 1] * Lk[32 + i]
                  + nv[k4 + 2] * Lk[64 + i] + nv[k4 + 3] * Lk[96 + i];
    }
#pragma unroll
    for (int i = 0; i < 32; i++) h[i] = h[i] * hsc + hbias[i];

    // AMRM pass 1: s_l = sum relu(ab_l + h@aW_l) * aa
    float s[3];
#pragma unroll
    for (int l = 0; l < 3; l++) {
        const float* A = aW + (size_t)l * 1024;
#pragma unroll
        for (int i = 0; i < 32; i++) acc[i] = ab[l * 32 + i];
        for (int k4 = 0; k4 < 32; k4 += 4) {
            const float* Ak = A + k4 * 32;
#pragma unroll
            for (int i = 0; i < 32; i++)
                acc[i] += h[k4] * Ak[i] + h[k4 + 1] * Ak[32 + i]
                        + h[k4 + 2] * Ak[64 + i] + h[k4 + 3] * Ak[96 + i];
        }
        float sl = 0.f;
#pragma unroll
        for (int i = 0; i < 32; i++) {
            float lv = acc[i] > 0.f ? acc[i] : 0.f;
            sl += lv * aa[i];
        }
        s[l] = sl;
    }
    float mx = fmaxf(s[0], fmaxf(s[1], s[2]));
    float e0 = __expf(s[0] - mx), e1 = __expf(s[1] - mx), e2 = __expf(s[2] - mx);
    float inv = 1.f / (e0 + e1 + e2);
    float scl[3] = {e0 * inv, e1 * inv, e2 * inv};

    // AMRM pass 2
    float outv[32];
#pragma unroll
    for (int i = 0; i < 32; i++) outv[i] = 0.f;
#pragma unroll
    for (int l = 0; l < 3; l++) {
        const float* A = aW + (size_t)l * 1024;
#pragma unroll
        for (int i = 0; i < 32; i++) acc[i] = ab[l * 32 + i];
        for (int k4 = 0; k4 < 32; k4 += 4) {
            const float* Ak = A + k4 * 32;
#pragma unroll
            for (int i = 0; i < 32; i++)
                acc[i] += h[k4] * Ak[i] + h[k4 + 1] * Ak[32 + i]
                        + h[k4 + 2] * Ak[64 + i] + h[k4 + 3] * Ak[96 + i];
        }
#pragma unroll
        for (int i = 0; i < 32; i++) {
            float lv = acc[i] > 0.f ? acc[i] : 0.f;
            outv[i] += scl[l] * lv;
        }
    }
    float* op = out + (size_t)n * 32;
#pragma unroll
    for (int i = 0; i < 32; i += 4)
        *(float4*)&op[i] = make_float4(fmaxf(outv[i], 0.f), fmaxf(outv[i + 1], 0.f),
                                       fmaxf(outv[i + 2], 0.f), fmaxf(outv[i + 3], 0.f));
}

// ---------------- host ----------------

static void launch_layer(const float* feat, const float* nf, const float* efeat,
                         const int* src, const int* dst, const int* eid,
                         const float* Wr, const float* attw, const float* lw,
                         const float* hb, const float* aW, const float* ab,
                         const float* aa, float* wsf, int* wsi, float* out,
                         hipStream_t stream) {
    k_prevec<<<1, 384, 0, stream>>>(Wr, attw, wsf + O_VV);
    k_nodeproj<<<391, 128, 0, stream>>>(feat, nf, attw, wsf + O_VV, wsi + O_DEGOUT,
                                        wsf + O_FEATN, wsf + O_NFT,
                                        wsf + O_ZF, wsf + O_ZNRD);
    k_ez<<<3125, 256, 0, stream>>>(src, dst, eid, efeat, wsf + O_ZF, wsf + O_ZNRD,
                                   wsf + O_VV, wsf + O_EZ);
    k_agg<<<6250, 512, 0, stream>>>(wsi + O_ROWPTR, (const int2*)(wsi + O_EINFO),
                                    wsf + O_EZ, efeat, wsf + O_FEATN,
                                    wsf + O_YACCT, wsf + O_WDENT);
    k_post<<<196, 256, 0, stream>>>(wsi + O_ROWPTR, wsf + O_YACCT, wsf + O_WDENT,
                                    wsf + O_NFT, Wr, lw, hb, aW, ab, aa, out);
}

extern "C" void kernel_launch(void* const* d_in, const int* in_sizes, int n_in,
                              void* d_out, int out_size, void* d_ws, size_t ws_size,
                              hipStream_t stream) {
    const float* x     = (const float*)d_in[0];
    const float* nfeat = (const float*)d_in[1];
    const float* efeat = (const float*)d_in[2];
    const int*   src   = (const int*)d_in[3];
    const int*   dst   = (const int*)d_in[4];
    const int*   eid   = (const int*)d_in[5];
    const float* Wr1   = (const float*)d_in[6];
    const float* attw1 = (const float*)d_in[7];
    const float* lw1   = (const float*)d_in[8];
    const float* hb1   = (const float*)d_in[9];
    const float* aW1   = (const float*)d_in[10];
    const float* ab1   = (const float*)d_in[11];
    const float* aa1   = (const float*)d_in[12];
    const float* Wr2   = (const float*)d_in[13];
    const float* attw2 = (const float*)d_in[14];
    const float* lw2   = (const float*)d_in[15];
    const float* hb2   = (const float*)d_in[16];
    const float* aW2   = (const float*)d_in[17];
    const float* ab2   = (const float*)d_in[18];
    const float* aa2   = (const float*)d_in[19];

    float* wsf = (float*)d_ws;
    int*   wsi = (int*)d_ws;
    float* out = (float*)d_out;

    // zero degree counters (degin + degout)
    hipMemsetAsync(d_ws, 0, (size_t)O_ROWPTR * 4, stream);

    k_deg<<<NE / 256, 256, 0, stream>>>(src, dst, wsi + O_DEGIN, wsi + O_DEGOUT);
    k_scan<<<1, 1024, 0, stream>>>(wsi + O_DEGIN, wsi + O_ROWPTR, wsi + O_CURSOR);
    k_scatter<<<NE / 256, 256, 0, stream>>>(src, dst, eid, wsi + O_CURSOR,
                                            (int2*)(wsi + O_EINFO));

    // layer 1: feat = x -> h1 (ws)
    launch_layer(x, nfeat, efeat, src, dst, eid, Wr1, attw1, lw1, hb1, aW1, ab1, aa1,
                 wsf, wsi, wsf + O_H1, stream);
    // layer 2: feat = h1 -> d_out
    launch_layer(wsf + O_H1, nfeat, efeat, src, dst, eid, Wr2, attw2, lw2, hb2,
                 aW2, ab2, aa2, wsf, wsi, out, stream);
}

// Round 7
// 703.845 us; speedup vs baseline: 1.0815x; 1.0815x over previous
//
#include <hip/hip_runtime.h>

#define NN 50000
#define NE 800000

// ws element offsets (4-byte units), 64-aligned; O_EINFO 8B-aligned
#define O_DEGIN   0
#define O_DEGOUT  50048
#define O_ROWPTR  100096
#define O_CURSOR  150208
#define O_EINFO   200256
#define O_FEATN   1800256
#define O_ZF      3400256
#define O_ZNRD    3600320
#define O_VV      3800384
#define O_EZ      3800832
#define O_NFT     4600832
#define O_WDENT   6200832
#define O_YACCT   6450880
#define O_H1      19250880
#define O_PACC    20850880
// end 27250880 elems = ~109 MB

// ---------------- setup kernels ----------------

__global__ __launch_bounds__(256) void k_deg(const int* __restrict__ src,
                                             const int* __restrict__ dst,
                                             int* degin, int* degout) {
    int e = blockIdx.x * 256 + threadIdx.x;
    if (e < NE) {
        atomicAdd(&degin[dst[e]], 1);
        atomicAdd(&degout[src[e]], 1);
    }
}

// single block, shuffle-based scan
__global__ __launch_bounds__(1024) void k_scan(const int* __restrict__ degin,
                                               int* rowptr, int* cursor) {
    __shared__ int swsum[16];
    __shared__ int stot;
    int t = threadIdx.x;
    int lane = t & 63, w = t >> 6;
    int carry = 0;
    for (int ch = 0; ch < 4; ch++) {
        int base = ch * 16384 + t * 16;
        int v[16];
        int s = 0;
#pragma unroll
        for (int j = 0; j < 16; j++) {
            v[j] = (base + j < NN) ? degin[base + j] : 0;
            s += v[j];
        }
        int incl = s;
#pragma unroll
        for (int off = 1; off < 64; off <<= 1) {
            int x = __shfl_up(incl, off, 64);
            if (lane >= off) incl += x;
        }
        if (lane == 63) swsum[w] = incl;
        __syncthreads();
        if (w == 0) {
            int y = (lane < 16) ? swsum[lane] : 0;
            int yi = y;
#pragma unroll
            for (int off = 1; off < 16; off <<= 1) {
                int x = __shfl_up(yi, off, 64);
                if (lane >= off) yi += x;
            }
            if (lane < 16) swsum[lane] = yi - y;
            if (lane == 15) stot = yi;
        }
        __syncthreads();
        int excl = carry + swsum[w] + (incl - s);
#pragma unroll
        for (int j = 0; j < 16; j++) {
            if (base + j < NN) { rowptr[base + j] = excl; cursor[base + j] = excl; }
            excl += v[j];
        }
        carry += stot;
        __syncthreads();
    }
    if (t == 0) rowptr[NN] = carry;
}

__global__ __launch_bounds__(256) void k_scatter(const int* __restrict__ src,
                                                 const int* __restrict__ dst,
                                                 const int* __restrict__ eid,
                                                 int* cursor, int2* einfo) {
    int e = blockIdx.x * 256 + threadIdx.x;
    if (e >= NE) return;
    int slot = atomicAdd(&cursor[dst[e]], 1);
    einfo[slot] = make_int2(src[e] | (eid[e] << 20), e);
}

// ---------------- per-layer kernels ----------------

// vvec[0:128]=ve[r][k] (We_r@aw2), [128:256]=vf[r][k], [256:384]=vd[r][k]
__global__ __launch_bounds__(384) void k_prevec(const float* __restrict__ Wr,
                                                const float* __restrict__ attw,
                                                float* __restrict__ vvec) {
    int t = threadIdx.x;
    int r = (t >> 5) & 3, k = t & 31, part = t >> 7;
    int row = (part == 0) ? (32 + k) : (part == 1) ? k : (64 + k);
    const float* wrow = Wr + (size_t)r * 3072 + row * 32;
    float s = 0.f;
#pragma unroll
    for (int c = 0; c < 32; c++) s += wrow[c] * attw[32 + c];
    vvec[t] = s;
}

// Thread per node: featn row, nfT column, zF[r][n], znrd[r][n]
__global__ __launch_bounds__(128) void k_nodeproj(const float* __restrict__ feat,
                                                  const float* __restrict__ nfeat,
                                                  const float* __restrict__ attw,
                                                  const float* __restrict__ vvec,
                                                  const int* __restrict__ degout,
                                                  float* __restrict__ featn,
                                                  float* __restrict__ nfT,
                                                  float* __restrict__ zF,
                                                  float* __restrict__ znrd) {
    int n = blockIdx.x * 128 + threadIdx.x;
    if (n >= NN) return;
    int dg = degout[n];
    float sc0 = rsqrtf((float)(dg > 1 ? dg : 1));
    const float* fin = feat + (size_t)n * 32;
    const float* nin = nfeat + (size_t)n * 32;
    float fv[32], nv[32];
#pragma unroll
    for (int k = 0; k < 32; k += 4) {
        float4 f4 = *(const float4*)&fin[k];
        fv[k] = f4.x * sc0; fv[k + 1] = f4.y * sc0;
        fv[k + 2] = f4.z * sc0; fv[k + 3] = f4.w * sc0;
        float4 n4 = *(const float4*)&nin[k];
        nv[k] = n4.x; nv[k + 1] = n4.y; nv[k + 2] = n4.z; nv[k + 3] = n4.w;
    }
    float* fo = featn + (size_t)n * 32;
#pragma unroll
    for (int k = 0; k < 32; k += 4)
        *(float4*)&fo[k] = make_float4(fv[k], fv[k + 1], fv[k + 2], fv[k + 3]);
#pragma unroll
    for (int k = 0; k < 32; k++) nfT[(size_t)k * NN + n] = nv[k];
    float zn = 0.f;
#pragma unroll
    for (int k = 0; k < 32; k++) zn += nv[k] * attw[k];
#pragma unroll
    for (int r = 0; r < 4; r++) {
        float zf = 0.f, zd = 0.f;
        const float* vf = vvec + 128 + r * 32;
        const float* vd = vvec + 256 + r * 32;
#pragma unroll
        for (int k = 0; k < 32; k++) { zf += fv[k] * vf[k]; zd += nv[k] * vd[k]; }
        zF[r * NN + n] = zf;
        znrd[r * NN + n] = zn + zd;
    }
}

// Flat edge-parallel: ez[e] = exp(leaky(znrd[r][d] + zF[r][s] + efeat[e].ve_r))
__global__ __launch_bounds__(256) void k_ez(const int* __restrict__ src,
                                            const int* __restrict__ dst,
                                            const int* __restrict__ eid,
                                            const float* __restrict__ efeat,
                                            const float* __restrict__ zF,
                                            const float* __restrict__ znrd,
                                            const float* __restrict__ vvec,
                                            float* __restrict__ ez) {
    int e = blockIdx.x * 256 + threadIdx.x;   // 3125*256 = NE exact
    int s = src[e], d = dst[e], r = eid[e];
    const float* er = efeat + (size_t)e * 32;
    float d0 = 0.f, d1 = 0.f, d2 = 0.f, d3 = 0.f;
#pragma unroll
    for (int k = 0; k < 32; k += 4) {
        float4 f = *(const float4*)&er[k];
        d0 += f.x * vvec[k]       + f.y * vvec[k + 1]
            + f.z * vvec[k + 2]   + f.w * vvec[k + 3];
        d1 += f.x * vvec[32 + k]  + f.y * vvec[33 + k]
            + f.z * vvec[34 + k]  + f.w * vvec[35 + k];
        d2 += f.x * vvec[64 + k]  + f.y * vvec[65 + k]
            + f.z * vvec[66 + k]  + f.w * vvec[67 + k];
        d3 += f.x * vvec[96 + k]  + f.y * vvec[97 + k]
            + f.z * vvec[98 + k]  + f.w * vvec[99 + k];
    }
    float dot = (r == 0) ? d0 : (r == 1) ? d1 : (r == 2) ? d2 : d3;
    float z = znrd[r * NN + d] + zF[r * NN + s] + dot;
    z = z > 0.f ? z : 0.01f * z;      // leaky_relu
    ez[e] = __expf(z);                // softmax max-shift cancels
}

// Wave per node, lane=(p,c): ez-weighted raw-row accumulation, pipelined
// gathers; output transposed via LDS -> yaccT[k][n].
__global__ __launch_bounds__(512) void k_agg(const int* __restrict__ rowptr,
                                             const int2* __restrict__ einfo,
                                             const float* __restrict__ ez,
                                             const float* __restrict__ efeat,
                                             const float* __restrict__ featn,
                                             float* __restrict__ yaccT,
                                             float* __restrict__ wdenT) {
    __shared__ float sT[256 * 9];
    int tid = threadIdx.x;
    int lane = tid & 63;
    int wid = tid >> 6;
    int n0 = blockIdx.x * 8;
    int n = n0 + wid;
    int c = lane & 31;
    int p = lane >> 5;

    int rp0 = rowptr[n];
    int deg = rowptr[n + 1] - rp0;

    float yf0 = 0.f, yf1 = 0.f, yf2 = 0.f, yf3 = 0.f;
    float ye0 = 0.f, ye1 = 0.f, ye2 = 0.f, ye3 = 0.f;
    float w0 = 0.f, w1 = 0.f, w2 = 0.f, w3 = 0.f, den = 0.f;

    int2 meA = make_int2(0, 0), meB = make_int2(0, 0);
    float ezA = 0.f, efA = 0.f, fnA = 0.f;
    if (p < deg) {
        meA = einfo[rp0 + p];
        ezA = ez[meA.y];
        efA = efeat[(size_t)meA.y * 32 + c];
        fnA = featn[(size_t)(meA.x & 0xFFFFF) * 32 + c];
    }
    if (p + 2 < deg) meB = einfo[rp0 + p + 2];

    for (int t = p; t < deg; t += 2) {
        float ezB = 0.f, efB = 0.f, fnB = 0.f;
        int2 meC = make_int2(0, 0);
        if (t + 2 < deg) {
            ezB = ez[meB.y];
            efB = efeat[(size_t)meB.y * 32 + c];
            fnB = featn[(size_t)(meB.x & 0xFFFFF) * 32 + c];
        }
        if (t + 4 < deg) meC = einfo[rp0 + t + 4];
        int rb = meA.x >> 20;
        float e0 = (rb == 0) ? ezA : 0.f;
        float e1 = (rb == 1) ? ezA : 0.f;
        float e2 = (rb == 2) ? ezA : 0.f;
        float e3 = (rb == 3) ? ezA : 0.f;
        yf0 += e0 * fnA; yf1 += e1 * fnA; yf2 += e2 * fnA; yf3 += e3 * fnA;
        ye0 += e0 * efA; ye1 += e1 * efA; ye2 += e2 * efA; ye3 += e3 * efA;
        w0 += e0; w1 += e1; w2 += e2; w3 += e3;
        den += ezA;
        meA = meB; ezA = ezB; efA = efB; fnA = fnB; meB = meC;
    }

    yf0 += __shfl_xor(yf0, 32); yf1 += __shfl_xor(yf1, 32);
    yf2 += __shfl_xor(yf2, 32); yf3 += __shfl_xor(yf3, 32);
    ye0 += __shfl_xor(ye0, 32); ye1 += __shfl_xor(ye1, 32);
    ye2 += __shfl_xor(ye2, 32); ye3 += __shfl_xor(ye3, 32);
    w0 += __shfl_xor(w0, 32); w1 += __shfl_xor(w1, 32);
    w2 += __shfl_xor(w2, 32); w3 += __shfl_xor(w3, 32);
    den += __shfl_xor(den, 32);

    if (lane < 5) {
        float wv = (lane == 0) ? w0 : (lane == 1) ? w1 : (lane == 2) ? w2
                 : (lane == 3) ? w3 : den;
        wdenT[lane * NN + n] = wv;
    }

    {
        int kb = 128 * p + c;
        sT[(kb +  0) * 9 + wid] = p ? ye0 : yf0;
        sT[(kb + 32) * 9 + wid] = p ? ye1 : yf1;
        sT[(kb + 64) * 9 + wid] = p ? ye2 : yf2;
        sT[(kb + 96) * 9 + wid] = p ? ye3 : yf3;
    }
    __syncthreads();
    int k = tid >> 1, hf = tid & 1;
    float4 v = make_float4(sT[k * 9 + hf * 4 + 0], sT[k * 9 + hf * 4 + 1],
                           sT[k * 9 + hf * 4 + 2], sT[k * 9 + hf * 4 + 3]);
    *(float4*)&yaccT[(size_t)k * NN + n0 + hf * 4] = v;
}

// Partial epilogue GEMV, relation chunk q = blockIdx.y (block-uniform ->
// weights stay wave-uniform/SGPR). Thread per node, 96 k-terms per chunk.
// pacc[(q*32+i)*NN + n] = sum_k uf*Wf_r + ue*We_r + (wr*nf)*Wd_r.
__global__ __launch_bounds__(256) void k_postA(const float* __restrict__ yaccT,
                                               const float* __restrict__ wdenT,
                                               const float* __restrict__ nfT,
                                               const float* __restrict__ Wr,
                                               float* __restrict__ pacc) {
    int n = blockIdx.x * 256 + threadIdx.x;
    if (n >= NN) return;
    int r = blockIdx.y;

    float nv[32];
#pragma unroll
    for (int k = 0; k < 32; k++) nv[k] = nfT[(size_t)k * NN + n];
    float wr = wdenT[r * NN + n];

    const float* W = Wr + (size_t)r * 3072;
    const float* ufc = yaccT + (size_t)(r * 32) * NN + n;
    const float* uec = yaccT + (size_t)(128 + r * 32) * NN + n;

    float acc[32];
#pragma unroll
    for (int i = 0; i < 32; i++) acc[i] = 0.f;
    for (int k4 = 0; k4 < 32; k4 += 4) {
        float a0 = ufc[(size_t)(k4 + 0) * NN], a1 = ufc[(size_t)(k4 + 1) * NN];
        float a2 = ufc[(size_t)(k4 + 2) * NN], a3 = ufc[(size_t)(k4 + 3) * NN];
        float b0 = uec[(size_t)(k4 + 0) * NN], b1 = uec[(size_t)(k4 + 1) * NN];
        float b2 = uec[(size_t)(k4 + 2) * NN], b3 = uec[(size_t)(k4 + 3) * NN];
        float g0 = wr * nv[k4],     g1 = wr * nv[k4 + 1];
        float g2 = wr * nv[k4 + 2], g3 = wr * nv[k4 + 3];
        const float* Wk = W + k4 * 32;
#pragma unroll
        for (int i = 0; i < 32; i++)
            acc[i] += a0 * Wk[i]        + a1 * Wk[32 + i]
                    + a2 * Wk[64 + i]   + a3 * Wk[96 + i]
                    + b0 * Wk[1024 + i] + b1 * Wk[1056 + i]
                    + b2 * Wk[1088 + i] + b3 * Wk[1120 + i]
                    + g0 * Wk[2048 + i] + g1 * Wk[2080 + i]
                    + g2 * Wk[2112 + i] + g3 * Wk[2144 + i];
    }
    float* po = pacc + (size_t)(r * 32) * NN + n;
#pragma unroll
    for (int i = 0; i < 32; i++) po[(size_t)i * NN] = acc[i];
}

// Thread per node: reduce 4 partials, + nf@lw (outside attention norm),
// normalize + bias, fused AMRM + relu -> out.
__global__ __launch_bounds__(256) void k_postB(const int* __restrict__ rowptr,
                                               const float* __restrict__ pacc,
                                               const float* __restrict__ wdenT,
                                               const float* __restrict__ nfT,
                                               const float* __restrict__ lw,
                                               const float* __restrict__ hbias,
                                               const float* __restrict__ aW,
                                               const float* __restrict__ ab,
                                               const float* __restrict__ aa,
                                               float* __restrict__ out) {
    int n = blockIdx.x * 256 + threadIdx.x;
    if (n >= NN) return;
    int deg = rowptr[n + 1] - rowptr[n];
    float den = wdenT[4 * NN + n];
    float invden = (deg > 0) ? 1.f / den : 0.f;

    float nv[32];
#pragma unroll
    for (int k = 0; k < 32; k++) nv[k] = nfT[(size_t)k * NN + n];

    float h[32];
#pragma unroll
    for (int i = 0; i < 32; i++) {
        float s = pacc[(size_t)i * NN + n]
                + pacc[(size_t)(32 + i) * NN + n]
                + pacc[(size_t)(64 + i) * NN + n]
                + pacc[(size_t)(96 + i) * NN + n];
        h[i] = s * invden;
    }
    for (int k4 = 0; k4 < 32; k4 += 4) {
        const float* Lk = lw + k4 * 32;
#pragma unroll
        for (int i = 0; i < 32; i++)
            h[i] += nv[k4] * Lk[i] + nv[k4 + 1] * Lk[32 + i]
                  + nv[k4 + 2] * Lk[64 + i] + nv[k4 + 3] * Lk[96 + i];
    }
    float hsc = rsqrtf((float)(deg > 1 ? deg : 1));
#pragma unroll
    for (int i = 0; i < 32; i++) h[i] = h[i] * hsc + hbias[i];

    float acc[32];
    float s[3];
#pragma unroll
    for (int l = 0; l < 3; l++) {
        const float* A = aW + (size_t)l * 1024;
#pragma unroll
        for (int i = 0; i < 32; i++) acc[i] = ab[l * 32 + i];
        for (int k4 = 0; k4 < 32; k4 += 4) {
            const float* Ak = A + k4 * 32;
#pragma unroll
            for (int i = 0; i < 32; i++)
                acc[i] += h[k4] * Ak[i] + h[k4 + 1] * Ak[32 + i]
                        + h[k4 + 2] * Ak[64 + i] + h[k4 + 3] * Ak[96 + i];
        }
        float sl = 0.f;
#pragma unroll
        for (int i = 0; i < 32; i++) {
            float lv = acc[i] > 0.f ? acc[i] : 0.f;
            sl += lv * aa[i];
        }
        s[l] = sl;
    }
    float mx = fmaxf(s[0], fmaxf(s[1], s[2]));
    float e0 = __expf(s[0] - mx), e1 = __expf(s[1] - mx), e2 = __expf(s[2] - mx);
    float inv = 1.f / (e0 + e1 + e2);
    float scl[3] = {e0 * inv, e1 * inv, e2 * inv};

    float outv[32];
#pragma unroll
    for (int i = 0; i < 32; i++) outv[i] = 0.f;
#pragma unroll
    for (int l = 0; l < 3; l++) {
        const float* A = aW + (size_t)l * 1024;
#pragma unroll
        for (int i = 0; i < 32; i++) acc[i] = ab[l * 32 + i];
        for (int k4 = 0; k4 < 32; k4 += 4) {
            const float* Ak = A + k4 * 32;
#pragma unroll
            for (int i = 0; i < 32; i++)
                acc[i] += h[k4] * Ak[i] + h[k4 + 1] * Ak[32 + i]
                        + h[k4 + 2] * Ak[64 + i] + h[k4 + 3] * Ak[96 + i];
        }
#pragma unroll
        for (int i = 0; i < 32; i++) {
            float lv = acc[i] > 0.f ? acc[i] : 0.f;
            outv[i] += scl[l] * lv;
        }
    }
    float* op = out + (size_t)n * 32;
#pragma unroll
    for (int i = 0; i < 32; i += 4)
        *(float4*)&op[i] = make_float4(fmaxf(outv[i], 0.f), fmaxf(outv[i + 1], 0.f),
                                       fmaxf(outv[i + 2], 0.f), fmaxf(outv[i + 3], 0.f));
}

// ---------------- host ----------------

static void launch_layer(const float* feat, const float* nf, const float* efeat,
                         const int* src, const int* dst, const int* eid,
                         const float* Wr, const float* attw, const float* lw,
                         const float* hb, const float* aW, const float* ab,
                         const float* aa, float* wsf, int* wsi, float* out,
                         hipStream_t stream) {
    k_prevec<<<1, 384, 0, stream>>>(Wr, attw, wsf + O_VV);
    k_nodeproj<<<391, 128, 0, stream>>>(feat, nf, attw, wsf + O_VV, wsi + O_DEGOUT,
                                        wsf + O_FEATN, wsf + O_NFT,
                                        wsf + O_ZF, wsf + O_ZNRD);
    k_ez<<<3125, 256, 0, stream>>>(src, dst, eid, efeat, wsf + O_ZF, wsf + O_ZNRD,
                                   wsf + O_VV, wsf + O_EZ);
    k_agg<<<6250, 512, 0, stream>>>(wsi + O_ROWPTR, (const int2*)(wsi + O_EINFO),
                                    wsf + O_EZ, efeat, wsf + O_FEATN,
                                    wsf + O_YACCT, wsf + O_WDENT);
    k_postA<<<dim3(196, 4), 256, 0, stream>>>(wsf + O_YACCT, wsf + O_WDENT,
                                              wsf + O_NFT, Wr, wsf + O_PACC);
    k_postB<<<196, 256, 0, stream>>>(wsi + O_ROWPTR, wsf + O_PACC, wsf + O_WDENT,
                                     wsf + O_NFT, lw, hb, aW, ab, aa, out);
}

extern "C" void kernel_launch(void* const* d_in, const int* in_sizes, int n_in,
                              void* d_out, int out_size, void* d_ws, size_t ws_size,
                              hipStream_t stream) {
    const float* x     = (const float*)d_in[0];
    const float* nfeat = (const float*)d_in[1];
    const float* efeat = (const float*)d_in[2];
    const int*   src   = (const int*)d_in[3];
    const int*   dst   = (const int*)d_in[4];
    const int*   eid   = (const int*)d_in[5];
    const float* Wr1   = (const float*)d_in[6];
    const float* attw1 = (const float*)d_in[7];
    const float* lw1   = (const float*)d_in[8];
    const float* hb1   = (const float*)d_in[9];
    const float* aW1   = (const float*)d_in[10];
    const float* ab1   = (const float*)d_in[11];
    const float* aa1   = (const float*)d_in[12];
    const float* Wr2   = (const float*)d_in[13];
    const float* attw2 = (const float*)d_in[14];
    const float* lw2   = (const float*)d_in[15];
    const float* hb2   = (const float*)d_in[16];
    const float* aW2   = (const float*)d_in[17];
    const float* ab2   = (const float*)d_in[18];
    const float* aa2   = (const float*)d_in[19];

    float* wsf = (float*)d_ws;
    int*   wsi = (int*)d_ws;
    float* out = (float*)d_out;

    // zero degree counters (degin + degout)
    hipMemsetAsync(d_ws, 0, (size_t)O_ROWPTR * 4, stream);

    k_deg<<<NE / 256, 256, 0, stream>>>(src, dst, wsi + O_DEGIN, wsi + O_DEGOUT);
    k_scan<<<1, 1024, 0, stream>>>(wsi + O_DEGIN, wsi + O_ROWPTR, wsi + O_CURSOR);
    k_scatter<<<NE / 256, 256, 0, stream>>>(src, dst, eid, wsi + O_CURSOR,
                                            (int2*)(wsi + O_EINFO));

    // layer 1: feat = x -> h1 (ws)
    launch_layer(x, nfeat, efeat, src, dst, eid, Wr1, attw1, lw1, hb1, aW1, ab1, aa1,
                 wsf, wsi, wsf + O_H1, stream);
    // layer 2: feat = h1 -> d_out
    launch_layer(wsf + O_H1, nfeat, efeat, src, dst, eid, Wr2, attw2, lw2, hb2,
                 aW2, ab2, aa2, wsf, wsi, out, stream);
}